// Round 1
// baseline (184.321 us; speedup 1.0000x reference)
//
#include <hip/hip_runtime.h>

// Problem constants (match reference)
#define BB 16
#define CC 256
#define HH 128
#define WW 128
#define RR 16          // C / RED
#define HWPLANE (HH * WW)          // 16384 floats per (b,c) plane
#define PLANE4  (HWPLANE / 4)      // 4096 float4 per plane

// ---------------------------------------------------------------------------
// Kernel 1: per-(b,c) hierarchical max pool + fused 21->1 per-channel linear.
// One block per plane. 256 threads, float4 loads over the contiguous 64 KiB
// plane. Key fact: rate-1/rate-2 pools are maxes over the 4x4 grid of 32x32
// block maxes (128/4 = 32), so we only compute the 16 block maxes.
// Thread t reads float4 index i*256+t -> col group fixed (bx = (t&31)>>3),
// row = i*8 + t/32 so by = i/4 (constant per unrolled outer step).
// ---------------------------------------------------------------------------
__global__ __launch_bounds__(256) void pool_fuse_kernel(
    const float* __restrict__ x,
    const float* __restrict__ Wf,   // (C, 21) row-major
    const float* __restrict__ bf,   // (C,)
    float* __restrict__ fused)      // (B*C,)
{
    const int bc = blockIdx.x;            // b*C + c
    const int c  = bc & (CC - 1);
    const float4* xp = (const float4*)(x + (size_t)bc * HWPLANE);

    const int t    = threadIdx.x;
    const int lane = t & 63;
    const int wave = t >> 6;
    const int bx   = (t & 31) >> 3;       // fixed column-block per thread

    __shared__ float wred[4][16];         // [wave][by*4+bx]
    __shared__ float pb[16];              // final 4x4 block maxes, by*4+bx

#pragma unroll
    for (int by = 0; by < 4; ++by) {
        float m = -3.402823466e+38f;
#pragma unroll
        for (int ii = 0; ii < 4; ++ii) {
            const int i = by * 4 + ii;    // compile-time constant
            float4 v = xp[i * 256 + t];
            m = fmaxf(m, fmaxf(fmaxf(v.x, v.y), fmaxf(v.z, v.w)));
        }
        // reduce over the 16 lanes sharing bx: xor within 8-group, then +-32
        m = fmaxf(m, __shfl_xor(m, 1));
        m = fmaxf(m, __shfl_xor(m, 2));
        m = fmaxf(m, __shfl_xor(m, 4));
        m = fmaxf(m, __shfl_xor(m, 32));
        if ((lane & 7) == 0 && lane < 32) wred[wave][by * 4 + bx] = m;
    }
    __syncthreads();

    if (t < 16) {
        pb[t] = fmaxf(fmaxf(wred[0][t], wred[1][t]),
                      fmaxf(wred[2][t], wred[3][t]));
    }
    __syncthreads();

    if (t == 0) {
        // rate-2 pools: quadrants of the 4x4 block-max grid (order by2*2+bx2)
        float q0 = fmaxf(fmaxf(pb[0],  pb[1]),  fmaxf(pb[4],  pb[5]));
        float q1 = fmaxf(fmaxf(pb[2],  pb[3]),  fmaxf(pb[6],  pb[7]));
        float q2 = fmaxf(fmaxf(pb[8],  pb[9]),  fmaxf(pb[12], pb[13]));
        float q3 = fmaxf(fmaxf(pb[10], pb[11]), fmaxf(pb[14], pb[15]));
        float g  = fmaxf(fmaxf(q0, q1), fmaxf(q2, q3));   // rate-1

        const float* w = Wf + c * 21;
        float acc = bf[c] + g * w[0]
                  + q0 * w[1] + q1 * w[2] + q2 * w[3] + q3 * w[4];
#pragma unroll
        for (int k = 0; k < 16; ++k) acc += pb[k] * w[5 + k];
        fused[bc] = acc;
    }
}

// ---------------------------------------------------------------------------
// Kernel 2: SE bottleneck. h = relu(fused @ W1 + b1); s = h @ W2 + b2.
// Tiny (B=16, C=256, r=16): one block, 256 threads.
// ---------------------------------------------------------------------------
__global__ __launch_bounds__(256) void se_kernel(
    const float* __restrict__ fused,  // (B*C,)
    const float* __restrict__ W1,     // (C, r)
    const float* __restrict__ b1,     // (r,)
    const float* __restrict__ W2,     // (r, C)
    const float* __restrict__ b2,     // (C,)
    float* __restrict__ s)            // (B*C,)
{
    __shared__ float hl[BB][RR];
    const int t = threadIdx.x;

    {   // h[b][j], 16x16 = 256 outputs, one per thread
        const int b = t >> 4, j = t & 15;
        float acc = b1[j];
        for (int cc = 0; cc < CC; ++cc)
            acc += fused[b * CC + cc] * W1[cc * RR + j];
        hl[b][j] = fmaxf(acc, 0.0f);
    }
    __syncthreads();

    // s[b][c]: thread t owns column c = t, loops over b
#pragma unroll
    for (int k = 0; k < BB; ++k) {
        float acc = b2[t];
#pragma unroll
        for (int j = 0; j < RR; ++j)
            acc += hl[k][j] * W2[j * CC + t];
        s[k * CC + t] = acc;
    }
}

// ---------------------------------------------------------------------------
// Kernel 3: out = x * s[b,c]. Pure streaming, float4, grid-stride.
// s is 16 KiB -> L1/L2 resident; 4 consecutive floats share (b,c).
// ---------------------------------------------------------------------------
__global__ __launch_bounds__(256) void scale_kernel(
    const float* __restrict__ x,
    const float* __restrict__ s,
    float* __restrict__ out,
    int n4)
{
    const int stride = gridDim.x * blockDim.x;
    for (int i = blockIdx.x * blockDim.x + threadIdx.x; i < n4; i += stride) {
        float4 v = ((const float4*)x)[i];
        float sc = s[i >> 12];            // 4096 float4 per plane
        float4 o;
        o.x = v.x * sc; o.y = v.y * sc; o.z = v.z * sc; o.w = v.w * sc;
        ((float4*)out)[i] = o;
    }
}

extern "C" void kernel_launch(void* const* d_in, const int* in_sizes, int n_in,
                              void* d_out, int out_size, void* d_ws, size_t ws_size,
                              hipStream_t stream) {
    const float* x  = (const float*)d_in[0];
    const float* Wf = (const float*)d_in[1];
    const float* bf = (const float*)d_in[2];
    const float* W1 = (const float*)d_in[3];
    const float* b1 = (const float*)d_in[4];
    const float* W2 = (const float*)d_in[5];
    const float* b2 = (const float*)d_in[6];
    float* out = (float*)d_out;

    float* fused = (float*)d_ws;          // B*C floats
    float* s     = fused + BB * CC;       // B*C floats

    pool_fuse_kernel<<<BB * CC, 256, 0, stream>>>(x, Wf, bf, fused);
    se_kernel<<<1, 256, 0, stream>>>(fused, W1, b1, W2, b2, s);

    const int n4 = BB * CC * PLANE4;      // 16,777,216 float4
    scale_kernel<<<2048, 256, 0, stream>>>(x, s, out, n4);
}

// Round 2
// 141.099 us; speedup vs baseline: 1.3063x; 1.3063x over previous
//
#include <hip/hip_runtime.h>

// Problem constants (match reference)
#define BB 16
#define CC 256
#define HH 128
#define WW 128
#define RR 16          // C / RED
#define HWPLANE (HH * WW)          // 16384 floats per (b,c) plane
#define PLANE4  (HWPLANE / 4)      // 4096 float4 per plane

using f32x4 = __attribute__((ext_vector_type(4))) float;

// ---------------------------------------------------------------------------
// Kernel 1: per-(b,c) hierarchical max pool + fused 21->1 per-channel linear.
// One block per plane. 256 threads, float4 loads over the contiguous 64 KiB
// plane. rate-1/rate-2 pools are maxes over the 4x4 grid of 32x32 block
// maxes, so we only compute the 16 block maxes.
// Regular (caching) loads on purpose: they populate L3 so kernel 3's re-read
// of x hits Infinity Cache (x = 256 MiB = L3 size).
// ---------------------------------------------------------------------------
__global__ __launch_bounds__(256) void pool_fuse_kernel(
    const float* __restrict__ x,
    const float* __restrict__ Wf,   // (C, 21) row-major
    const float* __restrict__ bf,   // (C,)
    float* __restrict__ fused)      // (B*C,)
{
    const int bc = blockIdx.x;            // b*C + c
    const int c  = bc & (CC - 1);
    const f32x4* xp = (const f32x4*)(x + (size_t)bc * HWPLANE);

    const int t    = threadIdx.x;
    const int lane = t & 63;
    const int wave = t >> 6;
    const int bx   = (t & 31) >> 3;       // fixed column-block per thread

    __shared__ float wred[4][16];         // [wave][by*4+bx]
    __shared__ float pb[16];              // final 4x4 block maxes, by*4+bx

#pragma unroll
    for (int by = 0; by < 4; ++by) {
        float m = -3.402823466e+38f;
#pragma unroll
        for (int ii = 0; ii < 4; ++ii) {
            const int i = by * 4 + ii;    // compile-time constant
            f32x4 v = xp[i * 256 + t];
            m = fmaxf(m, fmaxf(fmaxf(v.x, v.y), fmaxf(v.z, v.w)));
        }
        // reduce over the 16 lanes sharing bx: xor within 8-group, then +-32
        m = fmaxf(m, __shfl_xor(m, 1));
        m = fmaxf(m, __shfl_xor(m, 2));
        m = fmaxf(m, __shfl_xor(m, 4));
        m = fmaxf(m, __shfl_xor(m, 32));
        if ((lane & 7) == 0 && lane < 32) wred[wave][by * 4 + bx] = m;
    }
    __syncthreads();

    if (t < 16) {
        pb[t] = fmaxf(fmaxf(wred[0][t], wred[1][t]),
                      fmaxf(wred[2][t], wred[3][t]));
    }
    __syncthreads();

    if (t == 0) {
        // rate-2 pools: quadrants of the 4x4 block-max grid (order by2*2+bx2)
        float q0 = fmaxf(fmaxf(pb[0],  pb[1]),  fmaxf(pb[4],  pb[5]));
        float q1 = fmaxf(fmaxf(pb[2],  pb[3]),  fmaxf(pb[6],  pb[7]));
        float q2 = fmaxf(fmaxf(pb[8],  pb[9]),  fmaxf(pb[12], pb[13]));
        float q3 = fmaxf(fmaxf(pb[10], pb[11]), fmaxf(pb[14], pb[15]));
        float g  = fmaxf(fmaxf(q0, q1), fmaxf(q2, q3));   // rate-1

        const float* w = Wf + c * 21;
        float acc = bf[c] + g * w[0]
                  + q0 * w[1] + q1 * w[2] + q2 * w[3] + q3 * w[4];
#pragma unroll
        for (int k = 0; k < 16; ++k) acc += pb[k] * w[5 + k];
        fused[bc] = acc;
    }
}

// ---------------------------------------------------------------------------
// Kernel 2: SE bottleneck. h = relu(fused @ W1 + b1); s = h @ W2 + b2.
// Tiny (B=16, C=256, r=16): one block, 256 threads.
// ---------------------------------------------------------------------------
__global__ __launch_bounds__(256) void se_kernel(
    const float* __restrict__ fused,  // (B*C,)
    const float* __restrict__ W1,     // (C, r)
    const float* __restrict__ b1,     // (r,)
    const float* __restrict__ W2,     // (r, C)
    const float* __restrict__ b2,     // (C,)
    float* __restrict__ s)            // (B*C,)
{
    __shared__ float hl[BB][RR];
    const int t = threadIdx.x;

    {   // h[b][j], 16x16 = 256 outputs, one per thread
        const int b = t >> 4, j = t & 15;
        float acc = b1[j];
        for (int cc = 0; cc < CC; ++cc)
            acc += fused[b * CC + cc] * W1[cc * RR + j];
        hl[b][j] = fmaxf(acc, 0.0f);
    }
    __syncthreads();

    // s[b][c]: thread t owns column c = t, loops over b
#pragma unroll
    for (int k = 0; k < BB; ++k) {
        float acc = b2[t];
#pragma unroll
        for (int j = 0; j < RR; ++j)
            acc += hl[k][j] * W2[j * CC + t];
        s[k * CC + t] = acc;
    }
}

// ---------------------------------------------------------------------------
// Kernel 3: out = x * s[b,c]. One block per plane; s loaded once
// (wave-uniform scalar). Nontemporal stores for `out` so the write stream
// does NOT allocate in L2/L3 and evict x -> the x re-read hits Infinity
// Cache (populated by kernel 1).
// ---------------------------------------------------------------------------
__global__ __launch_bounds__(256) void scale_kernel(
    const float* __restrict__ x,
    const float* __restrict__ s,
    float* __restrict__ out)
{
    const int bc = blockIdx.x;
    const float sc = s[bc];               // uniform per block, L2-hit
    const f32x4* xp = (const f32x4*)(x + (size_t)bc * HWPLANE);
    f32x4* op = (f32x4*)(out + (size_t)bc * HWPLANE);
    const int t = threadIdx.x;

#pragma unroll
    for (int i = 0; i < 16; ++i) {
        f32x4 v = xp[i * 256 + t];
        f32x4 o = v * sc;
        __builtin_nontemporal_store(o, &op[i * 256 + t]);
    }
}

extern "C" void kernel_launch(void* const* d_in, const int* in_sizes, int n_in,
                              void* d_out, int out_size, void* d_ws, size_t ws_size,
                              hipStream_t stream) {
    const float* x  = (const float*)d_in[0];
    const float* Wf = (const float*)d_in[1];
    const float* bf = (const float*)d_in[2];
    const float* W1 = (const float*)d_in[3];
    const float* b1 = (const float*)d_in[4];
    const float* W2 = (const float*)d_in[5];
    const float* b2 = (const float*)d_in[6];
    float* out = (float*)d_out;

    float* fused = (float*)d_ws;          // B*C floats
    float* s     = fused + BB * CC;       // B*C floats

    pool_fuse_kernel<<<BB * CC, 256, 0, stream>>>(x, Wf, bf, fused);
    se_kernel<<<1, 256, 0, stream>>>(fused, W1, b1, W2, b2, s);
    scale_kernel<<<BB * CC, 256, 0, stream>>>(x, s, out);
}